// Round 5
// baseline (405.178 us; speedup 1.0000x reference)
//
#include <hip/hip_runtime.h>
#include <hip/hip_bf16.h>
#include <math.h>

typedef __attribute__((ext_vector_type(4))) float f32x4;
typedef __attribute__((ext_vector_type(8))) __bf16 bf16x8;
typedef unsigned short u16;
typedef __attribute__((ext_vector_type(4))) u16 u16x4;
typedef __attribute__((ext_vector_type(8))) u16 u16x8;

#define NTOK 16384
#define SEQ  4096

__device__ __forceinline__ void gload16(void* lds, const void* g) {
    __builtin_amdgcn_global_load_lds(
        (const __attribute__((address_space(1))) unsigned int*)g,
        (__attribute__((address_space(3))) unsigned int*)lds, 16, 0, 0);
}

// bijective XCD chunking; valid because nwg % 8 == 0 (ERRATA #11 safe form)
__device__ __forceinline__ int xcd_swizzle(int bid, int nwg) {
    int cpx = nwg >> 3;
    return (bid & 7) * cpx + (bid >> 3);
}

// ---------------- cast x (f32 -> bf16), 16B/lane stores ----------------
__global__ void cast_x_kernel(const float* __restrict__ in, __bf16* __restrict__ out, int n) {
    int stride = gridDim.x * blockDim.x * 8;
    for (int i = (blockIdx.x * blockDim.x + threadIdx.x) * 8; i < n; i += stride) {
        f32x4 v0 = *(const f32x4*)(in + i);
        f32x4 v1 = *(const f32x4*)(in + i + 4);
        u16x8 pk;
        pk[0] = __builtin_bit_cast(u16, (__bf16)v0.x);
        pk[1] = __builtin_bit_cast(u16, (__bf16)v0.y);
        pk[2] = __builtin_bit_cast(u16, (__bf16)v0.z);
        pk[3] = __builtin_bit_cast(u16, (__bf16)v0.w);
        pk[4] = __builtin_bit_cast(u16, (__bf16)v1.x);
        pk[5] = __builtin_bit_cast(u16, (__bf16)v1.y);
        pk[6] = __builtin_bit_cast(u16, (__bf16)v1.z);
        pk[7] = __builtin_bit_cast(u16, (__bf16)v1.w);
        *(u16x8*)(out + i) = pk;
    }
}

// ------------- transpose + cast: in[R][C] f32 -> out[C][R] bf16 -------------
__global__ void transpose_cast(const float* __restrict__ in, __bf16* __restrict__ out,
                               int R, int C) {
    __shared__ float t[32][33];
    int bx = blockIdx.x * 32;           // C index
    int by = blockIdx.y * 32;           // R index
    int tx = threadIdx.x & 31, ty = threadIdx.x >> 5;   // 32 x 8
    #pragma unroll
    for (int j = 0; j < 32; j += 8)
        t[ty + j][tx] = in[(size_t)(by + ty + j) * C + bx + tx];
    __syncthreads();
    #pragma unroll
    for (int j = 0; j < 32; j += 8)
        out[(size_t)(bx + ty + j) * R + by + tx] = (__bf16)t[tx][ty + j];
}

// ---------------- QKV GEMM: X[16384][1024] @ WqkvT -> Q, KT, VT ----------------
// 128x128 tile, BK=64, 4 waves (2x2), each 64x64 via 4x4 frags of 16x16x32.
__launch_bounds__(256)
__global__ void qkv_gemm(const __bf16* __restrict__ X,    // [16384][1024]
                         const __bf16* __restrict__ WT,   // [3072][1024]  (out-feature major)
                         __bf16* __restrict__ Q,          // [16384][1024]
                         __bf16* __restrict__ KT,         // [32][128][4096]
                         __bf16* __restrict__ VT) {       // [32][128][4096]
    __shared__ __bf16 As[128 * 64];
    __shared__ __bf16 Bs[128 * 64];
    const int swz = xcd_swizzle(blockIdx.x, 128 * 24);
    const int mblk = swz & 127;         // 0..127
    const int nblk = swz >> 7;          // 0..23
    const int tid = threadIdx.x;
    const int lane = tid & 63;
    const int wave = tid >> 6;
    const int wr = wave >> 1, wc = wave & 1;
    const int mBase = mblk * 128, nBase = nblk * 128;

    f32x4 acc[4][4] = {};

    for (int kt = 0; kt < 16; ++kt) {
        const int k0 = kt * 64;
        #pragma unroll
        for (int it = 0; it < 4; ++it) {
            int slot = it * 256 + tid;
            int r = slot >> 3, cs = slot & 7;
            int cg = cs ^ (r & 7);      // inverse-swizzled global source (rule #21)
            gload16((char*)As + slot * 16, X + (size_t)(mBase + r) * 1024 + k0 + cg * 8);
        }
        #pragma unroll
        for (int it = 0; it < 4; ++it) {
            int slot = it * 256 + tid;
            int r = slot >> 3, cs = slot & 7;
            int cg = cs ^ (r & 7);
            gload16((char*)Bs + slot * 16, WT + (size_t)(nBase + r) * 1024 + k0 + cg * 8);
        }
        __syncthreads();
        #pragma unroll
        for (int kk = 0; kk < 2; ++kk) {
            bf16x8 a[4], b[4];
            const int kb = kk * 4 + (lane >> 4);
            #pragma unroll
            for (int m = 0; m < 4; ++m) {
                int row = wr * 64 + m * 16 + (lane & 15);
                a[m] = *(const bf16x8*)((const char*)As + row * 128 + (kb ^ (row & 7)) * 16);
            }
            #pragma unroll
            for (int n = 0; n < 4; ++n) {
                int row = wc * 64 + n * 16 + (lane & 15);
                b[n] = *(const bf16x8*)((const char*)Bs + row * 128 + (kb ^ (row & 7)) * 16);
            }
            #pragma unroll
            for (int m = 0; m < 4; ++m)
                #pragma unroll
                for (int n = 0; n < 4; ++n)
                    acc[m][n] = __builtin_amdgcn_mfma_f32_16x16x32_bf16(a[m], b[n], acc[m][n], 0, 0, 0);
        }
        __syncthreads();
    }

    const int sec = nblk >> 3;          // 0=q 1=k 2=v
    const int head = nblk & 7;
    #pragma unroll
    for (int m = 0; m < 4; ++m) {
        const int row0 = mBase + wr * 64 + m * 16 + (lane >> 4) * 4;
        #pragma unroll
        for (int n = 0; n < 4; ++n) {
            const int col = wc * 64 + n * 16 + (lane & 15);   // 0..127 within head
            if (sec == 0) {
                #pragma unroll
                for (int j = 0; j < 4; ++j) {
                    float v = acc[m][n][j];
                    v = 1.0f / (1.0f + __expf(-v));           // sigmoid
                    Q[(size_t)(row0 + j) * 1024 + head * 128 + col] = (__bf16)v;
                }
            } else {
                u16x4 pk;
                #pragma unroll
                for (int j = 0; j < 4; ++j) {
                    float v = acc[m][n][j];
                    if (sec == 1) {                            // tanh, overflow-safe
                        float e = __expf(-2.0f * fabsf(v));
                        v = copysignf((1.0f - e) / (1.0f + e), v);
                    }
                    pk[j] = __builtin_bit_cast(u16, (__bf16)v);
                }
                const int b = row0 >> 12, nn = row0 & 4095;
                __bf16* dst = (sec == 1) ? KT : VT;
                *(u16x4*)(dst + ((size_t)(b * 8 + head) * 128 + col) * SEQ + nn) = pk;
            }
        }
    }
}

// ------- kv partials: per (b,h,chunk) kv_c = sum_{n in chunk} k^T v : [128][128] -------
// atomic-free split-K: KVp[bh][chunk][128][128] f32, summed in kvw_gemm.
__launch_bounds__(256)
__global__ void kv_gemm(const __bf16* __restrict__ KT, const __bf16* __restrict__ VT,
                        float* __restrict__ KVp) {
    const int bh = blockIdx.x >> 3;
    const int chunk = blockIdx.x & 7;
    const int tid = threadIdx.x, lane = tid & 63, wave = tid >> 6;
    const int wr = wave >> 1, wc = wave & 1;
    const __bf16* Kb = KT + (size_t)bh * 128 * SEQ;
    const __bf16* Vb = VT + (size_t)bh * 128 * SEQ;
    f32x4 acc[4][4] = {};
    const int nb = chunk * 512 + (lane >> 4) * 8;
    for (int ks = 0; ks < 16; ++ks) {
        const int n0 = nb + ks * 32;
        bf16x8 a[4], b[4];
        #pragma unroll
        for (int m = 0; m < 4; ++m) {
            int d = wr * 64 + m * 16 + (lane & 15);
            a[m] = *(const bf16x8*)(Kb + (size_t)d * SEQ + n0);
        }
        #pragma unroll
        for (int n = 0; n < 4; ++n) {
            int e = wc * 64 + n * 16 + (lane & 15);
            b[n] = *(const bf16x8*)(Vb + (size_t)e * SEQ + n0);
        }
        #pragma unroll
        for (int m = 0; m < 4; ++m)
            #pragma unroll
            for (int n = 0; n < 4; ++n)
                acc[m][n] = __builtin_amdgcn_mfma_f32_16x16x32_bf16(a[m], b[n], acc[m][n], 0, 0, 0);
    }
    float* out = KVp + ((size_t)bh * 8 + chunk) * 16384;
    #pragma unroll
    for (int m = 0; m < 4; ++m) {
        const int r0 = wr * 64 + m * 16 + (lane >> 4) * 4;
        #pragma unroll
        for (int n = 0; n < 4; ++n) {
            const int col = wc * 64 + n * 16 + (lane & 15);
            #pragma unroll
            for (int j = 0; j < 4; ++j)
                out[(r0 + j) * 128 + col] = acc[m][n][j];
        }
    }
}

// ---- MT[b][f][h*128+d] = sum_e (sum_c KVp[bh][c][d][e]) * WoT[f][h*128+e] ----
__launch_bounds__(256)
__global__ void kvw_gemm(const float* __restrict__ KVp, const __bf16* __restrict__ WoT,
                         __bf16* __restrict__ MT) {
    const int bh = blockIdx.x >> 3, ft = blockIdx.x & 7;
    const int b = bh >> 3, h = bh & 7;
    const int tid = threadIdx.x, lane = tid & 63, wave = tid >> 6;
    const int wr = wave >> 1, wc = wave & 1;
    const float* A = KVp + (size_t)bh * 8 * 16384;
    f32x4 acc[4][4] = {};
    for (int ks = 0; ks < 4; ++ks) {
        const int e0 = ks * 32 + (lane >> 4) * 8;
        bf16x8 a[4], bfr[4];
        #pragma unroll
        for (int m = 0; m < 4; ++m) {
            int d = wr * 64 + m * 16 + (lane & 15);
            f32x4 u = {0.f, 0.f, 0.f, 0.f};
            f32x4 w = {0.f, 0.f, 0.f, 0.f};
            #pragma unroll
            for (int c = 0; c < 8; ++c) {
                u += *(const f32x4*)(A + c * 16384 + d * 128 + e0);
                w += *(const f32x4*)(A + c * 16384 + d * 128 + e0 + 4);
            }
            bf16x8 t;
            t[0]=(__bf16)u.x; t[1]=(__bf16)u.y; t[2]=(__bf16)u.z; t[3]=(__bf16)u.w;
            t[4]=(__bf16)w.x; t[5]=(__bf16)w.y; t[6]=(__bf16)w.z; t[7]=(__bf16)w.w;
            a[m] = t;
        }
        #pragma unroll
        for (int n = 0; n < 4; ++n) {
            int f = ft * 128 + wc * 64 + n * 16 + (lane & 15);
            bfr[n] = *(const bf16x8*)(WoT + (size_t)f * 1024 + h * 128 + e0);
        }
        #pragma unroll
        for (int m = 0; m < 4; ++m)
            #pragma unroll
            for (int n = 0; n < 4; ++n)
                acc[m][n] = __builtin_amdgcn_mfma_f32_16x16x32_bf16(a[m], bfr[n], acc[m][n], 0, 0, 0);
    }
    __bf16* MTb = MT + (size_t)b * 1024 * 1024;
    #pragma unroll
    for (int m = 0; m < 4; ++m) {
        const int d0 = wr * 64 + m * 16 + (lane >> 4) * 4;
        #pragma unroll
        for (int n = 0; n < 4; ++n) {
            const int f = ft * 128 + wc * 64 + n * 16 + (lane & 15);
            u16x4 pk;
            #pragma unroll
            for (int j = 0; j < 4; ++j)
                pk[j] = __builtin_bit_cast(u16, (__bf16)acc[m][n][j]);
            *(u16x4*)(MTb + (size_t)f * 1024 + h * 128 + d0) = pk;
        }
    }
}

// ---------------- final: out[b] = Q[b] @ M[b] + bias (fp32 out) ----------------
__launch_bounds__(256)
__global__ void final_gemm(const __bf16* __restrict__ Q,   // [16384][1024]
                           const __bf16* __restrict__ MT,  // [4][1024 f][1024 k]
                           const float* __restrict__ bias,
                           float* __restrict__ out) {
    __shared__ __bf16 As[128 * 64];
    __shared__ __bf16 Bs[128 * 64];
    const int swz = xcd_swizzle(blockIdx.x, 128 * 8);
    const int mblk = swz & 127;         // 0..127
    const int nblk = swz >> 7;          // 0..7
    const int tid = threadIdx.x;
    const int lane = tid & 63;
    const int wave = tid >> 6;
    const int wr = wave >> 1, wc = wave & 1;
    const int mBase = mblk * 128, nBase = nblk * 128;
    const int b = mBase >> 12;
    const __bf16* Bsrc = MT + (size_t)b * 1024 * 1024;

    f32x4 acc[4][4] = {};

    for (int kt = 0; kt < 16; ++kt) {
        const int k0 = kt * 64;
        #pragma unroll
        for (int it = 0; it < 4; ++it) {
            int slot = it * 256 + tid;
            int r = slot >> 3, cs = slot & 7;
            int cg = cs ^ (r & 7);
            gload16((char*)As + slot * 16, Q + (size_t)(mBase + r) * 1024 + k0 + cg * 8);
        }
        #pragma unroll
        for (int it = 0; it < 4; ++it) {
            int slot = it * 256 + tid;
            int r = slot >> 3, cs = slot & 7;
            int cg = cs ^ (r & 7);
            gload16((char*)Bs + slot * 16, Bsrc + (size_t)(nBase + r) * 1024 + k0 + cg * 8);
        }
        __syncthreads();
        #pragma unroll
        for (int kk = 0; kk < 2; ++kk) {
            bf16x8 a[4], bfr[4];
            const int kb = kk * 4 + (lane >> 4);
            #pragma unroll
            for (int m = 0; m < 4; ++m) {
                int row = wr * 64 + m * 16 + (lane & 15);
                a[m] = *(const bf16x8*)((const char*)As + row * 128 + (kb ^ (row & 7)) * 16);
            }
            #pragma unroll
            for (int n = 0; n < 4; ++n) {
                int row = wc * 64 + n * 16 + (lane & 15);
                bfr[n] = *(const bf16x8*)((const char*)Bs + row * 128 + (kb ^ (row & 7)) * 16);
            }
            #pragma unroll
            for (int m = 0; m < 4; ++m)
                #pragma unroll
                for (int n = 0; n < 4; ++n)
                    acc[m][n] = __builtin_amdgcn_mfma_f32_16x16x32_bf16(a[m], bfr[n], acc[m][n], 0, 0, 0);
        }
        __syncthreads();
    }

    #pragma unroll
    for (int m = 0; m < 4; ++m) {
        const int row0 = mBase + wr * 64 + m * 16 + (lane >> 4) * 4;
        #pragma unroll
        for (int n = 0; n < 4; ++n) {
            const int col = nBase + wc * 64 + n * 16 + (lane & 15);
            const float bv = bias[col];
            #pragma unroll
            for (int j = 0; j < 4; ++j)
                out[(size_t)(row0 + j) * 1024 + col] = acc[m][n][j] + bv;
        }
    }
}

extern "C" void kernel_launch(void* const* d_in, const int* in_sizes, int n_in,
                              void* d_out, int out_size, void* d_ws, size_t ws_size,
                              hipStream_t stream) {
    const float* x    = (const float*)d_in[0];
    const float* Wqkv = (const float*)d_in[1];
    const float* Wout = (const float*)d_in[2];
    const float* bout = (const float*)d_in[3];
    float* out = (float*)d_out;
    char* ws = (char*)d_ws;
    char* ob = (char*)d_out;   // d_out (64 MiB fp32) doubles as scratch for
                               // intermediates dead before final_gemm runs.

    // --- scratch in d_out (fully overwritten by final_gemm at the end) ---
    __bf16* xb  = (__bf16*)(ob);                         // 32 MiB   [16384][1024]  (dead after qkv_gemm)
    float*  KVp = (float*)(ob + 33554432ull);            // 16 MiB   [32][8][128][128] (dead after kvw_gemm)
    // --- persistent scratch in ws: total 112 MiB ---
    __bf16* wqt = (__bf16*)(ws);                         // 6 MiB    [3072][1024]
    __bf16* wot = (__bf16*)(ws + 6291456ull);            // 2 MiB    [1024][1024]
    __bf16* Q   = (__bf16*)(ws + 8388608ull);            // 32 MiB   [16384][1024]
    __bf16* KT  = (__bf16*)(ws + 41943040ull);           // 32 MiB   [32][128][4096]
    __bf16* VT  = (__bf16*)(ws + 75497472ull);           // 32 MiB   [32][128][4096]
    __bf16* MT  = (__bf16*)(ws + 109051904ull);          // 8 MiB    [4][1024][1024]

    hipLaunchKernelGGL(cast_x_kernel, dim3(2048), dim3(256), 0, stream, x, xb, NTOK * 1024);
    hipLaunchKernelGGL(transpose_cast, dim3(96, 32), dim3(256), 0, stream, Wqkv, wqt, 1024, 3072);
    hipLaunchKernelGGL(transpose_cast, dim3(32, 32), dim3(256), 0, stream, Wout, wot, 1024, 1024);
    hipLaunchKernelGGL(qkv_gemm, dim3(128 * 24), dim3(256), 0, stream, xb, wqt, Q, KT, VT);
    hipLaunchKernelGGL(kv_gemm, dim3(256), dim3(256), 0, stream, KT, VT, KVp);
    hipLaunchKernelGGL(kvw_gemm, dim3(256), dim3(256), 0, stream, KVp, wot, MT);
    hipLaunchKernelGGL(final_gemm, dim3(128 * 8), dim3(256), 0, stream, Q, MT, bout, out);
}

// Round 9
// 385.472 us; speedup vs baseline: 1.0511x; 1.0511x over previous
//
#include <hip/hip_runtime.h>
#include <hip/hip_bf16.h>
#include <math.h>

typedef __attribute__((ext_vector_type(4))) float f32x4;
typedef __attribute__((ext_vector_type(8))) __bf16 bf16x8;
typedef unsigned short u16;
typedef __attribute__((ext_vector_type(4))) u16 u16x4;
typedef __attribute__((ext_vector_type(8))) u16 u16x8;

#define NTOK 16384
#define SEQ  4096

__device__ __forceinline__ void gload16(void* lds, const void* g) {
    __builtin_amdgcn_global_load_lds(
        (const __attribute__((address_space(1))) unsigned int*)g,
        (__attribute__((address_space(3))) unsigned int*)lds, 16, 0, 0);
}

// bijective XCD chunking; valid because nwg % 8 == 0 (ERRATA #11 safe form)
__device__ __forceinline__ int xcd_swizzle(int bid, int nwg) {
    int cpx = nwg >> 3;
    return (bid & 7) * cpx + (bid >> 3);
}

// ---------------- cast x (f32 -> bf16), 16B/lane stores ----------------
__global__ void cast_x_kernel(const float* __restrict__ in, __bf16* __restrict__ out, int n) {
    int stride = gridDim.x * blockDim.x * 8;
    for (int i = (blockIdx.x * blockDim.x + threadIdx.x) * 8; i < n; i += stride) {
        f32x4 v0 = *(const f32x4*)(in + i);
        f32x4 v1 = *(const f32x4*)(in + i + 4);
        u16x8 pk;
        pk[0] = __builtin_bit_cast(u16, (__bf16)v0.x);
        pk[1] = __builtin_bit_cast(u16, (__bf16)v0.y);
        pk[2] = __builtin_bit_cast(u16, (__bf16)v0.z);
        pk[3] = __builtin_bit_cast(u16, (__bf16)v0.w);
        pk[4] = __builtin_bit_cast(u16, (__bf16)v1.x);
        pk[5] = __builtin_bit_cast(u16, (__bf16)v1.y);
        pk[6] = __builtin_bit_cast(u16, (__bf16)v1.z);
        pk[7] = __builtin_bit_cast(u16, (__bf16)v1.w);
        *(u16x8*)(out + i) = pk;
    }
}

// ------------- transpose + cast: in[R][C] f32 -> out[C][R] bf16 -------------
__global__ void transpose_cast(const float* __restrict__ in, __bf16* __restrict__ out,
                               int R, int C) {
    __shared__ float t[32][33];
    int bx = blockIdx.x * 32;
    int by = blockIdx.y * 32;
    int tx = threadIdx.x & 31, ty = threadIdx.x >> 5;
    #pragma unroll
    for (int j = 0; j < 32; j += 8)
        t[ty + j][tx] = in[(size_t)(by + ty + j) * C + bx + tx];
    __syncthreads();
    #pragma unroll
    for (int j = 0; j < 32; j += 8)
        out[(size_t)(bx + ty + j) * R + by + tx] = (__bf16)t[tx][ty + j];
}

// =====================================================================
// 256x256-tile 8-phase GEMM core (T2 swizzle + T3/T4 counted vmcnt + T5).
// A [M][1024] bf16 row-major, B [N][1024] bf16 (out-feature-major).
// 8 waves (2M x 4N), per-wave C = 128x64. BK=64 as two 32-wide half-K-tiles.
// LDS: 4 A-slots + 4 B-slots of [256][32] bf16 (16KB each) = 128 KiB.
// Half-K-tile H_n: staged A@phase 2n-6, B@2n-5; read @ 2n..2n+1.
// s_waitcnt vmcnt(4) at p==3 and p==7 only: forces all but the newest
// half-pair complete; each H_n is complete one wait+barrier before its read.
// Tail (itr=7) clamps the stage SOURCE only; clamped re-stages land in
// slots whose computes already finished (verified slot/phase ledger).
// =====================================================================

#define PHASE(p)                                                                     \
    {                                                                                \
        constexpr int cs = (p) >> 1;            /* compute slot (static) */          \
        constexpr int nh = (p) & 1;             /* n-half */                         \
        constexpr int ss = (((p) >> 1) + 3) & 3;/* stage slot (static) */            \
        if constexpr (nh == 0) {                /* A-frags shared by both n-halves */\
            const char* ab = (const char*)AL + cs * 16384;                           \
            _Pragma("unroll")                                                        \
            for (int m = 0; m < 8; ++m)                                              \
                a[m] = *(const bf16x8*)(ab + aoff0 + m * 1024);                      \
        }                                                                            \
        bf16x8 b0, b1;                                                               \
        {                                                                            \
            const char* bb = (const char*)BL + cs * 16384;                           \
            b0 = *(const bf16x8*)(bb + boff0 + (nh * 2 + 0) * 1024);                 \
            b1 = *(const bf16x8*)(bb + boff0 + (nh * 2 + 1) * 1024);                 \
        }                                                                            \
        {   /* stage one half-tile: p even -> A of H_{4*itr+(p>>1)+3}, odd -> B */   \
            const int n = 4 * itr + ((p) >> 1) + 3;                                  \
            const int ns = n < 32 ? n : 31;     /* clamp SOURCE only */              \
            if constexpr (((p) & 1) == 0) {                                          \
                char* dst = (char*)AL + ss * 16384;                                  \
                gload16(dst + fb0, Asrc + ael0 + ns * 32);                           \
                gload16(dst + fb1, Asrc + ael1 + ns * 32);                           \
            } else {                                                                 \
                char* dst = (char*)BL + ss * 16384;                                  \
                gload16(dst + fb0, Bsrc + bel0 + ns * 32);                           \
                gload16(dst + fb1, Bsrc + bel1 + ns * 32);                           \
            }                                                                        \
        }                                                                            \
        if constexpr (((p) & 3) == 3) {                                              \
            asm volatile("s_waitcnt vmcnt(4)" ::: "memory");                         \
            __builtin_amdgcn_sched_barrier(0);                                       \
        }                                                                            \
        __builtin_amdgcn_s_barrier();                                                \
        __builtin_amdgcn_sched_barrier(0);                                           \
        __builtin_amdgcn_s_setprio(1);                                               \
        _Pragma("unroll")                                                            \
        for (int m = 0; m < 8; ++m) {                                                \
            acc[m][nh * 2 + 0] = __builtin_amdgcn_mfma_f32_16x16x32_bf16(            \
                a[m], b0, acc[m][nh * 2 + 0], 0, 0, 0);                              \
            acc[m][nh * 2 + 1] = __builtin_amdgcn_mfma_f32_16x16x32_bf16(            \
                a[m], b1, acc[m][nh * 2 + 1], 0, 0, 0);                              \
        }                                                                            \
        __builtin_amdgcn_s_setprio(0);                                               \
        __builtin_amdgcn_sched_barrier(0);                                           \
        __builtin_amdgcn_s_barrier();                                                \
    }

// shared setup for both 256^2 kernels (defines all locals PHASE uses)
#define GEMM256_SETUP(APTR, BPTR)                                                    \
    __shared__ __align__(16) __bf16 AL[4][256][32];                                  \
    __shared__ __align__(16) __bf16 BL[4][256][32];                                  \
    const int tid = threadIdx.x;                                                     \
    const int lane = tid & 63, wave = tid >> 6;                                      \
    const int wr = wave >> 2, wc = wave & 3;                                         \
    const __bf16* __restrict__ Asrc = (APTR);                                        \
    const __bf16* __restrict__ Bsrc = (BPTR);                                        \
    /* staging per-thread constants: two 16B chunks per half-tile */                 \
    const int fb0 = tid * 16, fb1 = (512 + tid) * 16;                                \
    const int srow0 = fb0 >> 6, sc0 = (fb0 >> 4) & 3;                                \
    const int srow1 = fb1 >> 6, sc1 = (fb1 >> 4) & 3;                                \
    const size_t ael0 = (size_t)(mBase + srow0) * 1024 + ((sc0 ^ (srow0 & 3)) << 3); \
    const size_t ael1 = (size_t)(mBase + srow1) * 1024 + ((sc1 ^ (srow1 & 3)) << 3); \
    const size_t bel0 = (size_t)(nBase + srow0) * 1024 + ((sc0 ^ (srow0 & 3)) << 3); \
    const size_t bel1 = (size_t)(nBase + srow1) * 1024 + ((sc1 ^ (srow1 & 3)) << 3); \
    /* ds_read per-thread base offsets (chunk = (lane>>4) ^ (row&3)) */              \
    const int aoff0 = (wr * 128 + (lane & 15)) * 64 + (((lane >> 4) ^ (lane & 3)) << 4); \
    const int boff0 = (wc * 64 + (lane & 15)) * 64 + (((lane >> 4) ^ (lane & 3)) << 4);  \
    f32x4 acc[8][4] = {};                                                            \
    bf16x8 a[8];                                                                     \
    /* prologue: stage H0,H1,H2 (A,B each); allow H2 in flight */                    \
    {                                                                                \
        _Pragma("unroll")                                                            \
        for (int n = 0; n < 3; ++n) {                                                \
            char* da = (char*)AL + n * 16384;                                        \
            char* db = (char*)BL + n * 16384;                                        \
            gload16(da + fb0, Asrc + ael0 + n * 32);                                 \
            gload16(da + fb1, Asrc + ael1 + n * 32);                                 \
            gload16(db + fb0, Bsrc + bel0 + n * 32);                                 \
            gload16(db + fb1, Bsrc + bel1 + n * 32);                                 \
        }                                                                            \
        asm volatile("s_waitcnt vmcnt(4)" ::: "memory");                             \
        __builtin_amdgcn_sched_barrier(0);                                           \
        __builtin_amdgcn_s_barrier();                                                \
    }                                                                                \
    _Pragma("unroll 1")                                                              \
    for (int itr = 0; itr < 8; ++itr) {                                              \
        PHASE(0) PHASE(1) PHASE(2) PHASE(3)                                          \
        PHASE(4) PHASE(5) PHASE(6) PHASE(7)                                          \
    }                                                                                \
    /* drain in-flight LDS-DMA before wave exit (LDS dealloc hazard) */              \
    asm volatile("s_waitcnt vmcnt(0)" ::: "memory");

// ------- QKV: X[16384][1024] @ WT[3072][1024] -> Q, KT, VT (fused act) -------
__launch_bounds__(512, 1)
__global__ void qkv_gemm256(const __bf16* __restrict__ X,
                            const __bf16* __restrict__ WT,
                            __bf16* __restrict__ Q,
                            __bf16* __restrict__ KT,
                            __bf16* __restrict__ VT) {
    const int swz = xcd_swizzle(blockIdx.x, 768);
    const int mblk = swz & 63, nblk = swz >> 6;     // 64 x 12
    const int mBase = mblk * 256, nBase = nblk * 256;
    GEMM256_SETUP(X, WT)

    const int sec = nblk >> 2;                      // 0=q 1=k 2=v
    const int colsec = (nblk & 3) * 256 + wc * 64;  // col within 1024 section
    #pragma unroll
    for (int m = 0; m < 8; ++m) {
        const int row = mBase + wr * 128 + m * 16 + (lane >> 4) * 4;
        const int b = row >> 12, nn = row & 4095;
        #pragma unroll
        for (int f = 0; f < 4; ++f) {
            const int colg = colsec + f * 16 + (lane & 15);
            if (sec == 0) {
                #pragma unroll
                for (int j = 0; j < 4; ++j) {
                    float v = acc[m][f][j];
                    v = 1.0f / (1.0f + __expf(-v));
                    Q[(size_t)(row + j) * 1024 + colg] = (__bf16)v;
                }
            } else {
                u16x4 pk;
                #pragma unroll
                for (int j = 0; j < 4; ++j) {
                    float v = acc[m][f][j];
                    if (sec == 1) {
                        float e = __expf(-2.0f * fabsf(v));
                        v = copysignf((1.0f - e) / (1.0f + e), v);
                    }
                    pk[j] = __builtin_bit_cast(u16, (__bf16)v);
                }
                const int head = colg >> 7, d = colg & 127;
                __bf16* dst = (sec == 1) ? KT : VT;
                *(u16x4*)(dst + ((size_t)(b * 8 + head) * 128 + d) * SEQ + nn) = pk;
            }
        }
    }
}

// ------- final: out[b] = Q[b] @ M[b]^T + bias (fp32 out) -------
__launch_bounds__(512, 1)
__global__ void final_gemm256(const __bf16* __restrict__ Qm,
                              const __bf16* __restrict__ MT,
                              const float* __restrict__ bias,
                              float* __restrict__ out) {
    const int swz = xcd_swizzle(blockIdx.x, 256);
    const int mblk = swz & 63, nblk = swz >> 6;     // 64 x 4
    const int mBase = mblk * 256, nBase = nblk * 256;
    const __bf16* Bbase = MT + (size_t)(mBase >> 12) * 1024 * 1024;
    GEMM256_SETUP(Qm, Bbase)

    #pragma unroll
    for (int m = 0; m < 8; ++m) {
        const int row = mBase + wr * 128 + m * 16 + (lane >> 4) * 4;
        #pragma unroll
        for (int f = 0; f < 4; ++f) {
            const int col = nBase + wc * 64 + f * 16 + (lane & 15);
            const float bv = bias[col];
            #pragma unroll
            for (int j = 0; j < 4; ++j)
                out[(size_t)(row + j) * 1024 + col] = acc[m][f][j] + bv;
        }
    }
}

// ------- kv partials: per (b,h,chunk) [128][128], atomic-free split-K -------
__launch_bounds__(256)
__global__ void kv_gemm(const __bf16* __restrict__ KT, const __bf16* __restrict__ VT,
                        float* __restrict__ KVp) {
    const int bh = blockIdx.x >> 3;
    const int chunk = blockIdx.x & 7;
    const int tid = threadIdx.x, lane = tid & 63, wave = tid >> 6;
    const int wr = wave >> 1, wc = wave & 1;
    const __bf16* Kb = KT + (size_t)bh * 128 * SEQ;
    const __bf16* Vb = VT + (size_t)bh * 128 * SEQ;
    f32x4 acc[4][4] = {};
    const int nb = chunk * 512 + (lane >> 4) * 8;
    for (int ks = 0; ks < 16; ++ks) {
        const int n0 = nb + ks * 32;
        bf16x8 a[4], b[4];
        #pragma unroll
        for (int m = 0; m < 4; ++m) {
            int d = wr * 64 + m * 16 + (lane & 15);
            a[m] = *(const bf16x8*)(Kb + (size_t)d * SEQ + n0);
        }
        #pragma unroll
        for (int n = 0; n < 4; ++n) {
            int e = wc * 64 + n * 16 + (lane & 15);
            b[n] = *(const bf16x8*)(Vb + (size_t)e * SEQ + n0);
        }
        #pragma unroll
        for (int m = 0; m < 4; ++m)
            #pragma unroll
            for (int n = 0; n < 4; ++n)
                acc[m][n] = __builtin_amdgcn_mfma_f32_16x16x32_bf16(a[m], b[n], acc[m][n], 0, 0, 0);
    }
    float* o = KVp + ((size_t)bh * 8 + chunk) * 16384;
    #pragma unroll
    for (int m = 0; m < 4; ++m) {
        const int r0 = wr * 64 + m * 16 + (lane >> 4) * 4;
        #pragma unroll
        for (int n = 0; n < 4; ++n) {
            const int col = wc * 64 + n * 16 + (lane & 15);
            #pragma unroll
            for (int j = 0; j < 4; ++j)
                o[(r0 + j) * 128 + col] = acc[m][n][j];
        }
    }
}

// ---- MT[b][f][h*128+d] = sum_e (sum_c KVp[bh][c][d][e]) * WoT[f][h*128+e] ----
__launch_bounds__(256)
__global__ void kvw_gemm(const float* __restrict__ KVp, const __bf16* __restrict__ WoT,
                         __bf16* __restrict__ MT) {
    const int bh = blockIdx.x >> 3, ft = blockIdx.x & 7;
    const int b = bh >> 3, h = bh & 7;
    const int tid = threadIdx.x, lane = tid & 63, wave = tid >> 6;
    const int wr = wave >> 1, wc = wave & 1;
    const float* A = KVp + (size_t)bh * 8 * 16384;
    f32x4 acc[4][4] = {};
    for (int ks = 0; ks < 4; ++ks) {
        const int e0 = ks * 32 + (lane >> 4) * 8;
        bf16x8 a[4], bfr[4];
        #pragma unroll
        for (int m = 0; m < 4; ++m) {
            int d = wr * 64 + m * 16 + (lane & 15);
            f32x4 u = {0.f, 0.f, 0.f, 0.f};
            f32x4 w = {0.f, 0.f, 0.f, 0.f};
            #pragma unroll
            for (int c = 0; c < 8; ++c) {
                u += *(const f32x4*)(A + c * 16384 + d * 128 + e0);
                w += *(const f32x4*)(A + c * 16384 + d * 128 + e0 + 4);
            }
            bf16x8 t;
            t[0]=(__bf16)u.x; t[1]=(__bf16)u.y; t[2]=(__bf16)u.z; t[3]=(__bf16)u.w;
            t[4]=(__bf16)w.x; t[5]=(__bf16)w.y; t[6]=(__bf16)w.z; t[7]=(__bf16)w.w;
            a[m] = t;
        }
        #pragma unroll
        for (int n = 0; n < 4; ++n) {
            int f = ft * 128 + wc * 64 + n * 16 + (lane & 15);
            bfr[n] = *(const bf16x8*)(WoT + (size_t)f * 1024 + h * 128 + e0);
        }
        #pragma unroll
        for (int m = 0; m < 4; ++m)
            #pragma unroll
            for (int n = 0; n < 4; ++n)
                acc[m][n] = __builtin_amdgcn_mfma_f32_16x16x32_bf16(a[m], bfr[n], acc[m][n], 0, 0, 0);
    }
    __bf16* MTb = MT + (size_t)b * 1024 * 1024;
    #pragma unroll
    for (int m = 0; m < 4; ++m) {
        const int d0 = wr * 64 + m * 16 + (lane >> 4) * 4;
        #pragma unroll
        for (int n = 0; n < 4; ++n) {
            const int f = ft * 128 + wc * 64 + n * 16 + (lane & 15);
            u16x4 pk;
            #pragma unroll
            for (int j = 0; j < 4; ++j)
                pk[j] = __builtin_bit_cast(u16, (__bf16)acc[m][n][j]);
            *(u16x4*)(MTb + (size_t)f * 1024 + h * 128 + d0) = pk;
        }
    }
}

extern "C" void kernel_launch(void* const* d_in, const int* in_sizes, int n_in,
                              void* d_out, int out_size, void* d_ws, size_t ws_size,
                              hipStream_t stream) {
    const float* x    = (const float*)d_in[0];
    const float* Wqkv = (const float*)d_in[1];
    const float* Wout = (const float*)d_in[2];
    const float* bout = (const float*)d_in[3];
    float* out = (float*)d_out;
    char* ws = (char*)d_ws;
    char* ob = (char*)d_out;   // d_out (64 MiB fp32) doubles as scratch

    // --- scratch in d_out (fully overwritten by final_gemm at the end) ---
    __bf16* xb  = (__bf16*)(ob);                         // 32 MiB  (dead after qkv)
    float*  KVp = (float*)(ob + 33554432ull);            // 16 MiB  (dead after kvw)
    // --- persistent scratch in ws: total 112 MiB ---
    __bf16* wqt = (__bf16*)(ws);                         // 6 MiB   [3072][1024]
    __bf16* wot = (__bf16*)(ws + 6291456ull);            // 2 MiB   [1024][1024]
    __bf16* Q   = (__bf16*)(ws + 8388608ull);            // 32 MiB  [16384][1024]
    __bf16* KT  = (__bf16*)(ws + 41943040ull);           // 32 MiB  [32][128][4096]
    __bf16* VT  = (__bf16*)(ws + 75497472ull);           // 32 MiB  [32][128][4096]
    __bf16* MT  = (__bf16*)(ws + 109051904ull);          // 8 MiB   [4][1024][1024]

    hipLaunchKernelGGL(cast_x_kernel, dim3(2048), dim3(256), 0, stream, x, xb, NTOK * 1024);
    hipLaunchKernelGGL(transpose_cast, dim3(96, 32), dim3(256), 0, stream, Wqkv, wqt, 1024, 3072);
    hipLaunchKernelGGL(transpose_cast, dim3(32, 32), dim3(256), 0, stream, Wout, wot, 1024, 1024);
    hipLaunchKernelGGL(qkv_gemm256, dim3(768), dim3(512), 0, stream, xb, wqt, Q, KT, VT);
    hipLaunchKernelGGL(kv_gemm, dim3(256), dim3(256), 0, stream, KT, VT, KVp);
    hipLaunchKernelGGL(kvw_gemm, dim3(256), dim3(256), 0, stream, KVp, wot, MT);
    hipLaunchKernelGGL(final_gemm256, dim3(256), dim3(512), 0, stream, Q, MT, bout, out);
}

// Round 13
// 373.807 us; speedup vs baseline: 1.0839x; 1.0312x over previous
//
#include <hip/hip_runtime.h>
#include <hip/hip_bf16.h>
#include <math.h>

typedef __attribute__((ext_vector_type(4))) float f32x4;
typedef __attribute__((ext_vector_type(8))) __bf16 bf16x8;
typedef unsigned short u16;
typedef __attribute__((ext_vector_type(4))) u16 u16x4;
typedef __attribute__((ext_vector_type(8))) u16 u16x8;

#define NTOK 16384
#define SEQ  4096

__device__ __forceinline__ void gload16(void* lds, const void* g) {
    __builtin_amdgcn_global_load_lds(
        (const __attribute__((address_space(1))) unsigned int*)g,
        (__attribute__((address_space(3))) unsigned int*)lds, 16, 0, 0);
}

// bijective XCD chunking; valid because nwg % 8 == 0 (ERRATA #11 safe form)
__device__ __forceinline__ int xcd_swizzle(int bid, int nwg) {
    int cpx = nwg >> 3;
    return (bid & 7) * cpx + (bid >> 3);
}

// ---------------- cast x (f32 -> bf16), 16B/lane stores ----------------
__global__ void cast_x_kernel(const float* __restrict__ in, __bf16* __restrict__ out, int n) {
    int stride = gridDim.x * blockDim.x * 8;
    for (int i = (blockIdx.x * blockDim.x + threadIdx.x) * 8; i < n; i += stride) {
        f32x4 v0 = *(const f32x4*)(in + i);
        f32x4 v1 = *(const f32x4*)(in + i + 4);
        u16x8 pk;
        pk[0] = __builtin_bit_cast(u16, (__bf16)v0.x);
        pk[1] = __builtin_bit_cast(u16, (__bf16)v0.y);
        pk[2] = __builtin_bit_cast(u16, (__bf16)v0.z);
        pk[3] = __builtin_bit_cast(u16, (__bf16)v0.w);
        pk[4] = __builtin_bit_cast(u16, (__bf16)v1.x);
        pk[5] = __builtin_bit_cast(u16, (__bf16)v1.y);
        pk[6] = __builtin_bit_cast(u16, (__bf16)v1.z);
        pk[7] = __builtin_bit_cast(u16, (__bf16)v1.w);
        *(u16x8*)(out + i) = pk;
    }
}

// ------------- transpose + cast: in[R][C] f32 -> out[C][R] bf16 -------------
__global__ void transpose_cast(const float* __restrict__ in, __bf16* __restrict__ out,
                               int R, int C) {
    __shared__ float t[32][33];
    int bx = blockIdx.x * 32;
    int by = blockIdx.y * 32;
    int tx = threadIdx.x & 31, ty = threadIdx.x >> 5;
    #pragma unroll
    for (int j = 0; j < 32; j += 8)
        t[ty + j][tx] = in[(size_t)(by + ty + j) * C + bx + tx];
    __syncthreads();
    #pragma unroll
    for (int j = 0; j < 32; j += 8)
        out[(size_t)(bx + ty + j) * R + by + tx] = (__bf16)t[tx][ty + j];
}

// =====================================================================
// 256x256-tile 8-phase GEMM core (T2 swizzle + T3/T4 counted vmcnt + T5).
// A [M][1024] bf16 row-major, B [N][1024] bf16 (out-feature-major).
// 8 waves (2M x 4N), per-wave C = 128x64. BK=64 as two 32-wide half-K-tiles.
// LDS: 4 A-slots + 4 B-slots of [256][32] bf16 (16KB each) = 128 KiB.
// Half-K-tile H_n: staged A@phase 2n-6, B@2n-5; read @ 2n..2n+1.
// s_waitcnt vmcnt(4) at p==3 and p==7 only.
// SWIZZLE KEY (r9 fix): s(row) = (row>>1)&3 — row&3 only spans {0,2} on
// same-parity rows -> 4-way bank conflict (9.4M measured); (row>>1)&3
// gives exactly 8 lanes per 16B bank-group (distribution-optimal).
// =====================================================================

#define PHASE(p)                                                                     \
    {                                                                                \
        constexpr int cs = (p) >> 1;            /* compute slot (static) */          \
        constexpr int nh = (p) & 1;             /* n-half */                         \
        constexpr int ss = (((p) >> 1) + 3) & 3;/* stage slot (static) */            \
        if constexpr (nh == 0) {                /* A-frags shared by both n-halves */\
            const char* ab = (const char*)AL + cs * 16384;                           \
            _Pragma("unroll")                                                        \
            for (int m = 0; m < 8; ++m)                                              \
                a[m] = *(const bf16x8*)(ab + aoff0 + m * 1024);                      \
        }                                                                            \
        bf16x8 b0, b1;                                                               \
        {                                                                            \
            const char* bb = (const char*)BL + cs * 16384;                           \
            b0 = *(const bf16x8*)(bb + boff0 + (nh * 2 + 0) * 1024);                 \
            b1 = *(const bf16x8*)(bb + boff0 + (nh * 2 + 1) * 1024);                 \
        }                                                                            \
        {   /* stage one half-tile: p even -> A of H_{4*itr+(p>>1)+3}, odd -> B */   \
            const int n = 4 * itr + ((p) >> 1) + 3;                                  \
            const int ns = n < 32 ? n : 31;     /* clamp SOURCE only */              \
            if constexpr (((p) & 1) == 0) {                                          \
                char* dst = (char*)AL + ss * 16384;                                  \
                gload16(dst + fb0, Asrc + ael0 + ns * 32);                           \
                gload16(dst + fb1, Asrc + ael1 + ns * 32);                           \
            } else {                                                                 \
                char* dst = (char*)BL + ss * 16384;                                  \
                gload16(dst + fb0, Bsrc + bel0 + ns * 32);                           \
                gload16(dst + fb1, Bsrc + bel1 + ns * 32);                           \
            }                                                                        \
        }                                                                            \
        if constexpr (((p) & 3) == 3) {                                              \
            asm volatile("s_waitcnt vmcnt(4)" ::: "memory");                         \
            __builtin_amdgcn_sched_barrier(0);                                       \
        }                                                                            \
        __builtin_amdgcn_s_barrier();                                                \
        __builtin_amdgcn_sched_barrier(0);                                           \
        __builtin_amdgcn_s_setprio(1);                                               \
        _Pragma("unroll")                                                            \
        for (int m = 0; m < 8; ++m) {                                                \
            acc[m][nh * 2 + 0] = __builtin_amdgcn_mfma_f32_16x16x32_bf16(            \
                a[m], b0, acc[m][nh * 2 + 0], 0, 0, 0);                              \
            acc[m][nh * 2 + 1] = __builtin_amdgcn_mfma_f32_16x16x32_bf16(            \
                a[m], b1, acc[m][nh * 2 + 1], 0, 0, 0);                              \
        }                                                                            \
        __builtin_amdgcn_s_setprio(0);                                               \
        __builtin_amdgcn_sched_barrier(0);                                           \
        __builtin_amdgcn_s_barrier();                                                \
    }

// shared setup for both 256^2 kernels (defines all locals PHASE uses)
#define GEMM256_SETUP(APTR, BPTR)                                                    \
    __shared__ __align__(16) __bf16 AL[4][256][32];                                  \
    __shared__ __align__(16) __bf16 BL[4][256][32];                                  \
    const int tid = threadIdx.x;                                                     \
    const int lane = tid & 63, wave = tid >> 6;                                      \
    const int wr = wave >> 2, wc = wave & 3;                                         \
    const __bf16* __restrict__ Asrc = (APTR);                                        \
    const __bf16* __restrict__ Bsrc = (BPTR);                                        \
    /* staging per-thread constants: two 16B chunks per half-tile */                 \
    const int fb0 = tid * 16, fb1 = (512 + tid) * 16;                                \
    const int srow0 = fb0 >> 6, sc0 = (fb0 >> 4) & 3;                                \
    const int srow1 = fb1 >> 6, sc1 = (fb1 >> 4) & 3;                                \
    const size_t ael0 = (size_t)(mBase + srow0) * 1024 + ((sc0 ^ ((srow0 >> 1) & 3)) << 3); \
    const size_t ael1 = (size_t)(mBase + srow1) * 1024 + ((sc1 ^ ((srow1 >> 1) & 3)) << 3); \
    const size_t bel0 = (size_t)(nBase + srow0) * 1024 + ((sc0 ^ ((srow0 >> 1) & 3)) << 3); \
    const size_t bel1 = (size_t)(nBase + srow1) * 1024 + ((sc1 ^ ((srow1 >> 1) & 3)) << 3); \
    /* ds_read base offsets: physical chunk = kc ^ ((row>>1)&3), row=lane&15 */      \
    const int aoff0 = (wr * 128 + (lane & 15)) * 64 + (((lane >> 4) ^ ((lane >> 1) & 3)) << 4); \
    const int boff0 = (wc * 64 + (lane & 15)) * 64 + (((lane >> 4) ^ ((lane >> 1) & 3)) << 4);  \
    f32x4 acc[8][4] = {};                                                            \
    bf16x8 a[8];                                                                     \
    /* prologue: stage H0,H1,H2 (A,B each); allow H2 in flight */                    \
    {                                                                                \
        _Pragma("unroll")                                                            \
        for (int n = 0; n < 3; ++n) {                                                \
            char* da = (char*)AL + n * 16384;                                        \
            char* db = (char*)BL + n * 16384;                                        \
            gload16(da + fb0, Asrc + ael0 + n * 32);                                 \
            gload16(da + fb1, Asrc + ael1 + n * 32);                                 \
            gload16(db + fb0, Bsrc + bel0 + n * 32);                                 \
            gload16(db + fb1, Bsrc + bel1 + n * 32);                                 \
        }                                                                            \
        asm volatile("s_waitcnt vmcnt(4)" ::: "memory");                             \
        __builtin_amdgcn_sched_barrier(0);                                           \
        __builtin_amdgcn_s_barrier();                                                \
    }                                                                                \
    _Pragma("unroll 1")                                                              \
    for (int itr = 0; itr < 8; ++itr) {                                              \
        PHASE(0) PHASE(1) PHASE(2) PHASE(3)                                          \
        PHASE(4) PHASE(5) PHASE(6) PHASE(7)                                          \
    }                                                                                \
    /* drain in-flight LDS-DMA before wave exit (LDS dealloc hazard) */              \
    asm volatile("s_waitcnt vmcnt(0)" ::: "memory");

// ------- QKV: X[16384][1024] @ WT[3072][1024] -> Q, KT, VT (fused act) -------
__launch_bounds__(512, 1)
__global__ void qkv_gemm256(const __bf16* __restrict__ X,
                            const __bf16* __restrict__ WT,
                            __bf16* __restrict__ Q,
                            __bf16* __restrict__ KT,
                            __bf16* __restrict__ VT) {
    const int swz = xcd_swizzle(blockIdx.x, 768);
    const int mblk = swz & 63, nblk = swz >> 6;     // 64 x 12
    const int mBase = mblk * 256, nBase = nblk * 256;
    GEMM256_SETUP(X, WT)

    const int sec = nblk >> 2;                      // 0=q 1=k 2=v
    const int colsec = (nblk & 3) * 256 + wc * 64;  // col within 1024 section
    #pragma unroll
    for (int m = 0; m < 8; ++m) {
        const int row = mBase + wr * 128 + m * 16 + (lane >> 4) * 4;
        const int b = row >> 12, nn = row & 4095;
        #pragma unroll
        for (int f = 0; f < 4; ++f) {
            const int colg = colsec + f * 16 + (lane & 15);
            if (sec == 0) {
                #pragma unroll
                for (int j = 0; j < 4; ++j) {
                    float v = acc[m][f][j];
                    v = 1.0f / (1.0f + __expf(-v));
                    Q[(size_t)(row + j) * 1024 + colg] = (__bf16)v;
                }
            } else {
                u16x4 pk;
                #pragma unroll
                for (int j = 0; j < 4; ++j) {
                    float v = acc[m][f][j];
                    if (sec == 1) {
                        float e = __expf(-2.0f * fabsf(v));
                        v = copysignf((1.0f - e) / (1.0f + e), v);
                    }
                    pk[j] = __builtin_bit_cast(u16, (__bf16)v);
                }
                const int head = colg >> 7, d = colg & 127;
                __bf16* dst = (sec == 1) ? KT : VT;
                *(u16x4*)(dst + ((size_t)(b * 8 + head) * 128 + d) * SEQ + nn) = pk;
            }
        }
    }
}

// ------- final: out[b] = Q[b] @ M[b]^T + bias (fp32 out) -------
__launch_bounds__(512, 1)
__global__ void final_gemm256(const __bf16* __restrict__ Qm,
                              const __bf16* __restrict__ MT,
                              const float* __restrict__ bias,
                              float* __restrict__ out) {
    const int swz = xcd_swizzle(blockIdx.x, 256);
    const int mblk = swz & 63, nblk = swz >> 6;     // 64 x 4
    const int mBase = mblk * 256, nBase = nblk * 256;
    const __bf16* Bbase = MT + (size_t)(mBase >> 12) * 1024 * 1024;
    GEMM256_SETUP(Qm, Bbase)

    #pragma unroll
    for (int m = 0; m < 8; ++m) {
        const int row = mBase + wr * 128 + m * 16 + (lane >> 4) * 4;
        #pragma unroll
        for (int f = 0; f < 4; ++f) {
            const int col = nBase + wc * 64 + f * 16 + (lane & 15);
            const float bv = bias[col];
            #pragma unroll
            for (int j = 0; j < 4; ++j)
                out[(size_t)(row + j) * 1024 + col] = acc[m][f][j] + bv;
        }
    }
}

// ------- kv partials: per (b,h,chunk) [128][128], atomic-free split-K -------
__launch_bounds__(256)
__global__ void kv_gemm(const __bf16* __restrict__ KT, const __bf16* __restrict__ VT,
                        float* __restrict__ KVp) {
    const int bh = blockIdx.x >> 3;
    const int chunk = blockIdx.x & 7;
    const int tid = threadIdx.x, lane = tid & 63, wave = tid >> 6;
    const int wr = wave >> 1, wc = wave & 1;
    const __bf16* Kb = KT + (size_t)bh * 128 * SEQ;
    const __bf16* Vb = VT + (size_t)bh * 128 * SEQ;
    f32x4 acc[4][4] = {};
    const int nb = chunk * 512 + (lane >> 4) * 8;
    for (int ks = 0; ks < 16; ++ks) {
        const int n0 = nb + ks * 32;
        bf16x8 a[4], b[4];
        #pragma unroll
        for (int m = 0; m < 4; ++m) {
            int d = wr * 64 + m * 16 + (lane & 15);
            a[m] = *(const bf16x8*)(Kb + (size_t)d * SEQ + n0);
        }
        #pragma unroll
        for (int n = 0; n < 4; ++n) {
            int e = wc * 64 + n * 16 + (lane & 15);
            b[n] = *(const bf16x8*)(Vb + (size_t)e * SEQ + n0);
        }
        #pragma unroll
        for (int m = 0; m < 4; ++m)
            #pragma unroll
            for (int n = 0; n < 4; ++n)
                acc[m][n] = __builtin_amdgcn_mfma_f32_16x16x32_bf16(a[m], b[n], acc[m][n], 0, 0, 0);
    }
    float* o = KVp + ((size_t)bh * 8 + chunk) * 16384;
    #pragma unroll
    for (int m = 0; m < 4; ++m) {
        const int r0 = wr * 64 + m * 16 + (lane >> 4) * 4;
        #pragma unroll
        for (int n = 0; n < 4; ++n) {
            const int col = wc * 64 + n * 16 + (lane & 15);
            #pragma unroll
            for (int j = 0; j < 4; ++j)
                o[(r0 + j) * 128 + col] = acc[m][n][j];
        }
    }
}

// ---- MT[b][f][h*128+d] = sum_e (sum_c KVp[bh][c][d][e]) * WoT[f][h*128+e] ----
__launch_bounds__(256)
__global__ void kvw_gemm(const float* __restrict__ KVp, const __bf16* __restrict__ WoT,
                         __bf16* __restrict__ MT) {
    const int bh = blockIdx.x >> 3, ft = blockIdx.x & 7;
    const int b = bh >> 3, h = bh & 7;
    const int tid = threadIdx.x, lane = tid & 63, wave = tid >> 6;
    const int wr = wave >> 1, wc = wave & 1;
    const float* A = KVp + (size_t)bh * 8 * 16384;
    f32x4 acc[4][4] = {};
    for (int ks = 0; ks < 4; ++ks) {
        const int e0 = ks * 32 + (lane >> 4) * 8;
        bf16x8 a[4], bfr[4];
        #pragma unroll
        for (int m = 0; m < 4; ++m) {
            int d = wr * 64 + m * 16 + (lane & 15);
            f32x4 u = {0.f, 0.f, 0.f, 0.f};
            f32x4 w = {0.f, 0.f, 0.f, 0.f};
            #pragma unroll
            for (int c = 0; c < 8; ++c) {
                u += *(const f32x4*)(A + c * 16384 + d * 128 + e0);
                w += *(const f32x4*)(A + c * 16384 + d * 128 + e0 + 4);
            }
            bf16x8 t;
            t[0]=(__bf16)u.x; t[1]=(__bf16)u.y; t[2]=(__bf16)u.z; t[3]=(__bf16)u.w;
            t[4]=(__bf16)w.x; t[5]=(__bf16)w.y; t[6]=(__bf16)w.z; t[7]=(__bf16)w.w;
            a[m] = t;
        }
        #pragma unroll
        for (int n = 0; n < 4; ++n) {
            int f = ft * 128 + wc * 64 + n * 16 + (lane & 15);
            bfr[n] = *(const bf16x8*)(WoT + (size_t)f * 1024 + h * 128 + e0);
        }
        #pragma unroll
        for (int m = 0; m < 4; ++m)
            #pragma unroll
            for (int n = 0; n < 4; ++n)
                acc[m][n] = __builtin_amdgcn_mfma_f32_16x16x32_bf16(a[m], bfr[n], acc[m][n], 0, 0, 0);
    }
    __bf16* MTb = MT + (size_t)b * 1024 * 1024;
    #pragma unroll
    for (int m = 0; m < 4; ++m) {
        const int d0 = wr * 64 + m * 16 + (lane >> 4) * 4;
        #pragma unroll
        for (int n = 0; n < 4; ++n) {
            const int f = ft * 128 + wc * 64 + n * 16 + (lane & 15);
            u16x4 pk;
            #pragma unroll
            for (int j = 0; j < 4; ++j)
                pk[j] = __builtin_bit_cast(u16, (__bf16)acc[m][n][j]);
            *(u16x4*)(MTb + (size_t)f * 1024 + h * 128 + d0) = pk;
        }
    }
}

extern "C" void kernel_launch(void* const* d_in, const int* in_sizes, int n_in,
                              void* d_out, int out_size, void* d_ws, size_t ws_size,
                              hipStream_t stream) {
    const float* x    = (const float*)d_in[0];
    const float* Wqkv = (const float*)d_in[1];
    const float* Wout = (const float*)d_in[2];
    const float* bout = (const float*)d_in[3];
    float* out = (float*)d_out;
    char* ws = (char*)d_ws;
    char* ob = (char*)d_out;   // d_out (64 MiB fp32) doubles as scratch

    // --- scratch in d_out (fully overwritten by final_gemm at the end) ---
    __bf16* xb  = (__bf16*)(ob);                         // 32 MiB  (dead after qkv)
    float*  KVp = (float*)(ob + 33554432ull);            // 16 MiB  (dead after kvw)
    // --- persistent scratch in ws: total 112 MiB ---
    __bf16* wqt = (__bf16*)(ws);                         // 6 MiB   [3072][1024]
    __bf16* wot = (__bf16*)(ws + 6291456ull);            // 2 MiB   [1024][1024]
    __bf16* Q   = (__bf16*)(ws + 8388608ull);            // 32 MiB  [16384][1024]
    __bf16* KT  = (__bf16*)(ws + 41943040ull);           // 32 MiB  [32][128][4096]
    __bf16* VT  = (__bf16*)(ws + 75497472ull);           // 32 MiB  [32][128][4096]
    __bf16* MT  = (__bf16*)(ws + 109051904ull);          // 8 MiB   [4][1024][1024]

    hipLaunchKernelGGL(cast_x_kernel, dim3(2048), dim3(256), 0, stream, x, xb, NTOK * 1024);
    hipLaunchKernelGGL(transpose_cast, dim3(96, 32), dim3(256), 0, stream, Wqkv, wqt, 1024, 3072);
    hipLaunchKernelGGL(transpose_cast, dim3(32, 32), dim3(256), 0, stream, Wout, wot, 1024, 1024);
    hipLaunchKernelGGL(qkv_gemm256, dim3(768), dim3(512), 0, stream, xb, wqt, Q, KT, VT);
    hipLaunchKernelGGL(kv_gemm, dim3(256), dim3(256), 0, stream, KT, VT, KVp);
    hipLaunchKernelGGL(kvw_gemm, dim3(256), dim3(256), 0, stream, KVp, wot, MT);
    hipLaunchKernelGGL(final_gemm256, dim3(256), dim3(512), 0, stream, Q, MT, bout, out);
}